// Round 7
// baseline (1137.732 us; speedup 1.0000x reference)
//
#include <hip/hip_runtime.h>

// Problem constants (fixed by setup_inputs)
constexpr int NDA = 10000;   // target graph nodes
constexpr int NQ  = 64;      // query graph nodes
constexpr int CND = 1024;    // candidate set size
constexpr int DIN = 128;     // input feature dim
constexpr int D   = 256;     // hidden dim
constexpr int CAP = 96;      // max nnz per adjacency row (Poisson(20); P(>96) ~ 0)
constexpr int NB64 = ((NDA + 63) / 64) * (D / 64);   // 628 blocks for 10000x256 gemm
constexpr int GCHUNK = 400;                           // G: 25 chunks x 400 rows
constexpr int NGB = 16 * (NDA / GCHUNK);              // 400 G blocks

#define LRELU(x) ((x) >= 0.f ? (x) : 0.01f * (x))

__device__ __forceinline__ float wave_red64(float v) {
#pragma unroll
    for (int o = 32; o; o >>= 1) v += __shfl_down(v, o);
    return v;
}

// Single compiled instance so the end-path and the G-inline-path produce
// BIT-IDENTICAL scores (threshold decisions must match exactly).
// Result valid on lane 0 of each wave.
__device__ __noinline__ float end_score(const float* __restrict__ ar,
                                        const float* se, float embn, int lane) {
    float num = 0.f, sq = 0.f;
#pragma unroll
    for (int s = 0; s < 4; s++) {
        float v = ar[lane + 64 * s];
        num += v * se[lane + 64 * s];
        sq += v * v;
    }
#pragma unroll
    for (int o = 32; o; o >>= 1) { num += __shfl_down(num, o); sq += __shfl_down(sq, o); }
    float den = fmaxf(sqrtf(sq) * embn, 1e-8f);
    return num / den;
}

// ---------------------------------------------------------------------------
// Per-stage shared-memory structs.
struct GemmSmem  { float As[32][65]; float Bs[32][68]; };   // 64x64 tile gemm (~17 KB)
struct CrossSmem { float qs[D]; float cmw[256]; int sci[256]; float red[4]; float sqn; float part[4][256]; };
struct SpmmSmem  { int sc[CAP]; float part[4][256]; };
struct CsrSmem   { int scnt; };
struct FinalSmem { int sc[CAP]; float part[4][256]; int n; int sdiag; float r1[4], r2[4], r3[4]; };
struct Attq4Smem { float hbuf[64][65]; float red[4][64]; float invs[64]; };
struct GSm  { float SA[8][64]; float SB[8][64]; float se[256]; float red[4]; float mrow[GCHUNK]; };
struct ESm  { float se[256]; float scnt; float red[4]; };

// ---------------------------------------------------------------------------
// 64x64-tile GEMM: 4x4/thread, K%32==0, register prefetch (~80 VGPR keeps
// merged-dispatch gather bodies at decent wave occupancy — round-5 lesson).
template <bool RELU_A, bool RELU_C>
__device__ __forceinline__ void gemm_body(GemmSmem& sm, int bx, int by,
                                          const float* __restrict__ A,
                                          const float* __restrict__ B,
                                          float* __restrict__ C,
                                          int M, int N, int K) {
    const int bm = bx * 64, bn = by * 64;
    const int tid = threadIdx.x;
    const int tx = tid & 15, ty = tid >> 4;
    const int lm = tid >> 2, lk = (tid & 3) * 8;
    const int kb = tid >> 3, nb = (tid & 7) * 8;
    const bool aValid = (bm + lm) < M;
    const float* aPtr = A + (size_t)(bm + lm) * K + lk;
    const float* bPtr = B + (size_t)kb * N + bn + nb;
    float4 ra0 = make_float4(0.f, 0.f, 0.f, 0.f), ra1 = ra0, rb0, rb1;
    if (aValid) { ra0 = *(const float4*)aPtr; ra1 = *(const float4*)(aPtr + 4); }
    rb0 = *(const float4*)bPtr;
    rb1 = *(const float4*)(bPtr + 4);
    float acc[4][4] = {};
    for (int k0 = 0; k0 < K; k0 += 32) {
        float4 wa0 = ra0, wa1 = ra1, wb0 = rb0, wb1 = rb1;
        if (RELU_A) {
            wa0.x = LRELU(wa0.x); wa0.y = LRELU(wa0.y); wa0.z = LRELU(wa0.z); wa0.w = LRELU(wa0.w);
            wa1.x = LRELU(wa1.x); wa1.y = LRELU(wa1.y); wa1.z = LRELU(wa1.z); wa1.w = LRELU(wa1.w);
        }
        sm.As[lk + 0][lm] = wa0.x; sm.As[lk + 1][lm] = wa0.y;
        sm.As[lk + 2][lm] = wa0.z; sm.As[lk + 3][lm] = wa0.w;
        sm.As[lk + 4][lm] = wa1.x; sm.As[lk + 5][lm] = wa1.y;
        sm.As[lk + 6][lm] = wa1.z; sm.As[lk + 7][lm] = wa1.w;
        *(float4*)&sm.Bs[kb][nb]     = wb0;
        *(float4*)&sm.Bs[kb][nb + 4] = wb1;
        __syncthreads();
        if (k0 + 32 < K) {
            if (aValid) {
                ra0 = *(const float4*)(aPtr + k0 + 32);
                ra1 = *(const float4*)(aPtr + k0 + 36);
            }
            rb0 = *(const float4*)(bPtr + (size_t)(k0 + 32) * N);
            rb1 = *(const float4*)(bPtr + (size_t)(k0 + 32) * N + 4);
        }
#pragma unroll
        for (int kk = 0; kk < 32; kk++) {
            float av[4], bv[4];
#pragma unroll
            for (int i = 0; i < 4; i++) av[i] = sm.As[kk][ty * 4 + i];
#pragma unroll
            for (int j = 0; j < 4; j++) bv[j] = sm.Bs[kk][tx * 4 + j];
#pragma unroll
            for (int i = 0; i < 4; i++)
#pragma unroll
                for (int j = 0; j < 4; j++) acc[i][j] += av[i] * bv[j];
        }
        __syncthreads();
    }
#pragma unroll
    for (int i = 0; i < 4; i++) {
        int r = bm + ty * 4 + i;
        if (r < M) {
            float4 v = make_float4(acc[i][0], acc[i][1], acc[i][2], acc[i][3]);
            if (RELU_C) { v.x = LRELU(v.x); v.y = LRELU(v.y); v.z = LRELU(v.z); v.w = LRELU(v.w); }
            *(float4*)(C + (size_t)r * N + bn + tx * 4) = v;
        }
    }
}

// ---------------------------------------------------------------------------
__device__ __forceinline__ void csr_body(CsrSmem& sm, const float* __restrict__ adj,
                                         int* __restrict__ cols,
                                         int* __restrict__ rowcnt, int row) {
    if (threadIdx.x == 0) sm.scnt = 0;
    __syncthreads();
    const float4* rp = (const float4*)(adj + (size_t)row * NDA);
    for (int i = threadIdx.x; i < NDA / 4; i += 256) {
        float4 v = rp[i];
        if (v.x != 0.f) { int s = atomicAdd(&sm.scnt, 1); if (s < CAP) cols[row * CAP + s] = 4 * i; }
        if (v.y != 0.f) { int s = atomicAdd(&sm.scnt, 1); if (s < CAP) cols[row * CAP + s] = 4 * i + 1; }
        if (v.z != 0.f) { int s = atomicAdd(&sm.scnt, 1); if (s < CAP) cols[row * CAP + s] = 4 * i + 2; }
        if (v.w != 0.f) { int s = atomicAdd(&sm.scnt, 1); if (s < CAP) cols[row * CAP + s] = 4 * i + 3; }
    }
    __syncthreads();
    if (threadIdx.x == 0) rowcnt[row] = min(sm.scnt, CAP);
}

// ---------------------------------------------------------------------------
// SpMM, wave-per-neighbor float4 gather, FOUR rows in flight (MLP depth 4).
__device__ __forceinline__ void spmm_body(SpmmSmem& sm, const int* __restrict__ cols,
                                          const int* __restrict__ rowcnt,
                                          const float* __restrict__ X,
                                          float* __restrict__ out1,
                                          float* __restrict__ out2, int row) {
    int t = threadIdx.x;
    int w = t >> 6, lane = t & 63;
    int cnt = rowcnt[row];
    if (t < cnt) sm.sc[t] = cols[row * CAP + t];
    __syncthreads();
    float4 acc = make_float4(0.f, 0.f, 0.f, 0.f);
    int k = w;
    for (; k + 12 < cnt; k += 16) {
        float4 v0 = ((const float4*)(X + (size_t)sm.sc[k]      * D))[lane];
        float4 v1 = ((const float4*)(X + (size_t)sm.sc[k + 4]  * D))[lane];
        float4 v2 = ((const float4*)(X + (size_t)sm.sc[k + 8]  * D))[lane];
        float4 v3 = ((const float4*)(X + (size_t)sm.sc[k + 12] * D))[lane];
        acc.x += (v0.x + v1.x) + (v2.x + v3.x);
        acc.y += (v0.y + v1.y) + (v2.y + v3.y);
        acc.z += (v0.z + v1.z) + (v2.z + v3.z);
        acc.w += (v0.w + v1.w) + (v2.w + v3.w);
    }
    for (; k < cnt; k += 4) {
        float4 v0 = ((const float4*)(X + (size_t)sm.sc[k] * D))[lane];
        acc.x += v0.x; acc.y += v0.y; acc.z += v0.z; acc.w += v0.w;
    }
    *(float4*)&sm.part[w][lane * 4] = acc;
    __syncthreads();
    float s = sm.part[0][t] + sm.part[1][t] + sm.part[2][t] + sm.part[3][t];
    float v = LRELU(s);
    out1[(size_t)row * D + t] = v;
    if (out2) out2[(size_t)row * D + t] = LRELU(v);
}

// ---------------------------------------------------------------------------
// Cross (rownorms+cosmat+hq fused).
__device__ __forceinline__ void cross_body(CrossSmem& sm, const float* __restrict__ q,
                                           const float* __restrict__ da,
                                           const int* __restrict__ cand,
                                           float* __restrict__ hpart,
                                           int r, int qr) {
    int t = threadIdx.x;
    int w = t >> 6, lane = t & 63;
    float qv = q[r * D + t];
    sm.qs[t] = qv;
    sm.sci[t] = cand[qr * 256 + t];
    float p = wave_red64(qv * qv);
    if (lane == 0) sm.red[w] = p;
    __syncthreads();
    if (t == 0) sm.sqn = fmaxf(sqrtf(sm.red[0] + sm.red[1] + sm.red[2] + sm.red[3]), 1e-12f);
    __syncthreads();
    float qn = sm.sqn;
    float4 qv4 = *(const float4*)&sm.qs[lane * 4];
    for (int c = w * 64; c < w * 64 + 64; c++) {
        const float4* rp = (const float4*)(da + (size_t)sm.sci[c] * D);
        float4 v = rp[lane];
        float dp = qv4.x * v.x + qv4.y * v.y + qv4.z * v.z + qv4.w * v.w;
        float sq = v.x * v.x + v.y * v.y + v.z * v.z + v.w * v.w;
#pragma unroll
        for (int o = 32; o; o >>= 1) { dp += __shfl_down(dp, o); sq += __shfl_down(sq, o); }
        if (lane == 0) sm.cmw[c] = dp / (qn * fmaxf(sqrtf(sq), 1e-12f));
    }
    __syncthreads();
    float4 acc = make_float4(0.f, 0.f, 0.f, 0.f);
    for (int c = w; c < 256; c += 8) {
        float w0 = sm.cmw[c], w1 = sm.cmw[c + 4];
        const float4* p0 = (const float4*)(da + (size_t)sm.sci[c] * D);
        const float4* p1 = (const float4*)(da + (size_t)sm.sci[c + 4] * D);
        float4 v0 = p0[lane];
        float4 v1 = p1[lane];
        acc.x += w0 * v0.x + w1 * v1.x;
        acc.y += w0 * v0.y + w1 * v1.y;
        acc.z += w0 * v0.z + w1 * v1.z;
        acc.w += w0 * v0.w + w1 * v1.w;
    }
    *(float4*)&sm.part[w][lane * 4] = acc;
    __syncthreads();
    float hs = sm.part[0][t] + sm.part[1][t] + sm.part[2][t] + sm.part[3][t];
    hpart[((size_t)qr * NQ + r) * D + t] = hs;
}

// ---------------------------------------------------------------------------
// Stage 0: [X1 gemm64 | Xq gemm64 | zero-G | CSR build]
__global__ __launch_bounds__(256) void stage0_kernel(const float* __restrict__ adj,
                                                     int* __restrict__ cols,
                                                     int* __restrict__ rowcnt,
                                                     const float* __restrict__ Fda,
                                                     const float* __restrict__ W1da,
                                                     float* __restrict__ X1,
                                                     const float* __restrict__ Fq,
                                                     const float* __restrict__ W1q,
                                                     float* __restrict__ Xq,
                                                     float* __restrict__ G) {
    __shared__ union { GemmSmem g; CsrSmem z; } sm;
    int bid = blockIdx.x;
    if (bid < NB64) {
        gemm_body<false, false>(sm.g, bid >> 2, bid & 3, Fda, W1da, X1, NDA, D, DIN);
    } else if (bid < NB64 + 4) {
        gemm_body<false, false>(sm.g, 0, bid - NB64, Fq, W1q, Xq, NQ, D, DIN);
    } else if (bid < NB64 + 20) {
        int zb = bid - (NB64 + 4);                 // 16 blocks zero G (64K floats)
        float4* g4 = (float4*)G;
        int base = zb * 1024 + threadIdx.x;
#pragma unroll
        for (int k = 0; k < 4; k++)
            g4[base + k * 256] = make_float4(0.f, 0.f, 0.f, 0.f);
    } else {
        csr_body(sm.z, adj, cols, rowcnt, bid - (NB64 + 20));
    }
}

// [q-gemm (Qadj @ xq, lrelu) | spmm over all target rows]
__global__ __launch_bounds__(256) void stage_sg_kernel(const int* __restrict__ cols,
                                                       const int* __restrict__ rowcnt,
                                                       const float* __restrict__ X,
                                                       float* __restrict__ out1,
                                                       float* __restrict__ out2,
                                                       const float* __restrict__ Aq,
                                                       const float* __restrict__ Bq,
                                                       float* __restrict__ Cq) {
    __shared__ union { GemmSmem g; SpmmSmem s; } sm;
    int bid = blockIdx.x;
    if (bid < 4) {
        gemm_body<false, true>(sm.g, 0, bid, Aq, Bq, Cq, NQ, D, NQ);
    } else {
        spmm_body(sm.s, cols, rowcnt, X, out1, out2, bid - 4);
    }
}

// [cross1 | Y2 = lrelu(da1) @ W2da]
__global__ __launch_bounds__(256) void mergeA_kernel(const float* __restrict__ q1,
                                                     const float* __restrict__ da1,
                                                     const int* __restrict__ cand,
                                                     float* __restrict__ hpart,
                                                     const float* __restrict__ W2da,
                                                     float* __restrict__ Y2) {
    __shared__ union { CrossSmem c; GemmSmem g; } sm;
    int bid = blockIdx.x;
    if (bid < 256) {
        cross_body(sm.c, q1, da1, cand, hpart, bid >> 2, bid & 3);
    } else {
        int t = bid - 256;
        gemm_body<true, false>(sm.g, t >> 2, t & 3, da1, W2da, Y2, NDA, D, D);
    }
}

// Standalone cross (layer 2)
__global__ __launch_bounds__(256) void cross_kernel(const float* __restrict__ q,
                                                    const float* __restrict__ da,
                                                    const int* __restrict__ cand,
                                                    float* __restrict__ hpart) {
    __shared__ CrossSmem sm;
    cross_body(sm, q, da, cand, hpart, blockIdx.x, blockIdx.y);
}

// ---------------------------------------------------------------------------
// qfused: attq1 computed straight into LDS (A^T layout), then Zq = aq1 @ W2q.
__global__ __launch_bounds__(256) void qfused_kernel(const float* __restrict__ q,
                                                     const float* __restrict__ hpart,
                                                     const float* __restrict__ W2q,
                                                     float* __restrict__ Zq) {
    __shared__ float aqT[D][65];   // A^T: [k][m], m = query row
    __shared__ float Bs[32][68];
    int d = threadIdx.x;
    float hv[NQ];
    float ss = 0.f;
#pragma unroll
    for (int r = 0; r < NQ; r++) {
        float h = hpart[(size_t)r * D + d]
                + hpart[(size_t)(NQ + r) * D + d]
                + hpart[(size_t)(2 * NQ + r) * D + d]
                + hpart[(size_t)(3 * NQ + r) * D + d];
        hv[r] = h;
        ss += h * h;
    }
    float inv = 1.f / fmaxf(sqrtf(ss), 1e-12f);
#pragma unroll
    for (int r = 0; r < NQ; r++) {
        float v = q[r * D + d] + hv[r] * inv;
        aqT[d][r] = LRELU(v);
    }
    __syncthreads();
    const int bn = blockIdx.x * 64;
    const int tx = d & 15, ty = d >> 4;
    const int kb = d >> 3, nb = (d & 7) * 8;
    float acc[4][4] = {};
    for (int k0 = 0; k0 < D; k0 += 32) {
        float4 b0 = *(const float4*)(W2q + (size_t)(k0 + kb) * D + bn + nb);
        float4 b1 = *(const float4*)(W2q + (size_t)(k0 + kb) * D + bn + nb + 4);
        *(float4*)&Bs[kb][nb]     = b0;
        *(float4*)&Bs[kb][nb + 4] = b1;
        __syncthreads();
#pragma unroll
        for (int kk = 0; kk < 32; kk++) {
            float av[4], bv[4];
#pragma unroll
            for (int i = 0; i < 4; i++) av[i] = aqT[k0 + kk][ty * 4 + i];
#pragma unroll
            for (int j = 0; j < 4; j++) bv[j] = Bs[kk][tx * 4 + j];
#pragma unroll
            for (int i = 0; i < 4; i++)
#pragma unroll
                for (int j = 0; j < 4; j++) acc[i][j] += av[i] * bv[j];
        }
        __syncthreads();
    }
#pragma unroll
    for (int i = 0; i < 4; i++) {
        float4 v = make_float4(acc[i][0], acc[i][1], acc[i][2], acc[i][3]);
        *(float4*)(Zq + (size_t)(ty * 4 + i) * D + bn + tx * 4) = v;
    }
}

// ---------------------------------------------------------------------------
// attq (4 blocks, 64 columns each): att_q2 = lrelu(q + h/colnorm(h)), emb = col
// means. Block 0 thread 0 also zero-inits the scalar accumulators.
__global__ __launch_bounds__(256) void attq4_kernel(const float* __restrict__ q,
                                                    const float* __restrict__ hpart,
                                                    float* __restrict__ attq,
                                                    float* __restrict__ emb,
                                                    float* __restrict__ cnt,
                                                    double* __restrict__ tot,
                                                    double* __restrict__ tr) {
    __shared__ Attq4Smem sm;
    int b = blockIdx.x, t = threadIdx.x;
    int lc = t & 63, rq = t >> 6;
    int c = b * 64 + lc;
    if (b == 0 && t == 0) { *cnt = 0.f; *tot = 0.0; *tr = 0.0; }
    float ss = 0.f;
#pragma unroll
    for (int rr = 0; rr < 16; rr++) {
        int r = rq * 16 + rr;
        float h = hpart[(size_t)r * D + c]
                + hpart[(size_t)(NQ + r) * D + c]
                + hpart[(size_t)(2 * NQ + r) * D + c]
                + hpart[(size_t)(3 * NQ + r) * D + c];
        sm.hbuf[r][lc] = h;
        ss += h * h;
    }
    sm.red[rq][lc] = ss;
    __syncthreads();
    if (rq == 0) {
        float s = sm.red[0][lc] + sm.red[1][lc] + sm.red[2][lc] + sm.red[3][lc];
        sm.invs[lc] = 1.f / fmaxf(sqrtf(s), 1e-12f);
    }
    __syncthreads();
    float inv = sm.invs[lc];
    float es = 0.f;
#pragma unroll
    for (int rr = 0; rr < 16; rr++) {
        int r = rq * 16 + rr;
        float v = q[r * D + c] + sm.hbuf[r][lc] * inv;
        v = LRELU(v);
        attq[r * D + c] = v;
        es += v;
    }
    __syncthreads();   // red[] reuse
    sm.red[rq][lc] = es;
    __syncthreads();
    if (rq == 0) {
        float e = (sm.red[0][lc] + sm.red[1][lc] + sm.red[2][lc] + sm.red[3][lc]) * (1.f / (float)NQ);
        emb[c] = e;
    }
}

// ---------------------------------------------------------------------------
// Merged [G | end] dispatch (consecutive serial stages in r6; G computes its
// mask inline via the SAME noinline end_score -> bit-identical decisions).
// G blocks first (long-running), end blocks pack around them.
__global__ __launch_bounds__(256) void endG_kernel(const float* __restrict__ A,
                                                   const float* __restrict__ emb,
                                                   const float* __restrict__ thr_p,
                                                   float* __restrict__ endv,
                                                   float* __restrict__ m,
                                                   float* __restrict__ cnt,
                                                   float* __restrict__ G) {
    __shared__ union { GSm g; ESm e; } sm;
    int bid = blockIdx.x;
    int t = threadIdx.x;
    int w = t >> 6, lane = t & 63;
    if (bid < NGB) {
        // ---- G block: G += sum_{i in chunk, m_i} a_i a_i^T (mask inline) ----
        int tile = bid & 15, chunk = bid >> 4;
        int ti = tile >> 2, tj = tile & 3;
        int base = chunk * GCHUNK;
        float ev = emb[t];
        sm.g.se[t] = ev;
        float pe = wave_red64(ev * ev);
        if (lane == 0) sm.g.red[w] = pe;
        __syncthreads();
        float embn = sqrtf(sm.g.red[0] + sm.g.red[1] + sm.g.red[2] + sm.g.red[3]);
        float thr = *thr_p;
        for (int rr = w; rr < GCHUNK; rr += 4) {
            const float* ar = A + (size_t)(base + rr) * D;
            float e = end_score(ar, sm.g.se, embn, lane);
            if (lane == 0) sm.g.mrow[rr] = e > thr ? 1.f : 0.f;
        }
        __syncthreads();
        int tx = t & 15, ty = t >> 4;
        float acc[4][4] = {};
        for (int g0 = 0; g0 < GCHUNK; g0 += 8) {
            for (int l = t; l < 512; l += 256) {
                int rr = l >> 6, c = l & 63;
                int r = base + g0 + rr;
                float mv = sm.g.mrow[g0 + rr];
                sm.g.SA[rr][c] = A[(size_t)r * D + ti * 64 + c] * mv;
                sm.g.SB[rr][c] = A[(size_t)r * D + tj * 64 + c];
            }
            __syncthreads();
#pragma unroll
            for (int rr = 0; rr < 8; rr++) {
                float av[4], bv[4];
#pragma unroll
                for (int i = 0; i < 4; i++) av[i] = sm.g.SA[rr][ty * 4 + i];
#pragma unroll
                for (int j = 0; j < 4; j++) bv[j] = sm.g.SB[rr][tx * 4 + j];
#pragma unroll
                for (int i = 0; i < 4; i++)
#pragma unroll
                    for (int j = 0; j < 4; j++) acc[i][j] += av[i] * bv[j];
            }
            __syncthreads();
        }
#pragma unroll
        for (int i = 0; i < 4; i++)
#pragma unroll
            for (int j = 0; j < 4; j++)
                atomicAdd(&G[(ti * 64 + ty * 4 + i) * D + tj * 64 + tx * 4 + j], acc[i][j]);
    } else {
        // ---- end block: endv / m / cnt for 4 rows ----
        int quad = bid - NGB;
        float ev = emb[t];
        sm.e.se[t] = ev;
        if (t == 0) sm.e.scnt = 0.f;
        float pe = wave_red64(ev * ev);
        if (lane == 0) sm.e.red[w] = pe;
        __syncthreads();
        float embn = sqrtf(sm.e.red[0] + sm.e.red[1] + sm.e.red[2] + sm.e.red[3]);
        float thr = *thr_p;
        int row = quad * 4 + w;
        const float* ar = A + (size_t)row * D;
        float e = end_score(ar, sm.e.se, embn, lane);
        if (lane == 0) {
            endv[row] = e;
            float mv = e > thr ? 1.f : 0.f;
            m[row] = mv;
            if (mv != 0.f) atomicAdd(&sm.e.scnt, 1.f);
        }
        __syncthreads();
        if (t == 0 && sm.e.scnt != 0.f) atomicAdd(cnt, sm.e.scnt);
    }
}

// H = att_da2 @ G  (gemm64, 628 blocks fills the GPU)
__global__ __launch_bounds__(256) void gemmH_kernel(const float* __restrict__ A,
                                                    const float* __restrict__ B,
                                                    float* __restrict__ C) {
    __shared__ GemmSmem sm;
    gemm_body<false, false>(sm, blockIdx.x, blockIdx.y, A, B, C, NDA, D, D);
}

// ---------------------------------------------------------------------------
// Final reduction per masked row i: compact masked neighbors into LDS, wave-
// per-neighbor float4 gather with MLP depth 4, then num/den2/self reduction.
__global__ __launch_bounds__(256) void final_kernel(const int* __restrict__ cols,
                                                    const int* __restrict__ rowcnt,
                                                    const float* __restrict__ m,
                                                    const float* __restrict__ A,
                                                    const float* __restrict__ H,
                                                    double* __restrict__ total,
                                                    double* __restrict__ tr) {
    int i = blockIdx.x;
    if (m[i] == 0.f) return;
    __shared__ FinalSmem sm;
    int t = threadIdx.x;
    int w = t >> 6, lane = t & 63;
    int cnt = rowcnt[i];
    if (t == 0) { sm.n = 0; sm.sdiag = 0; }
    __syncthreads();
    if (t < cnt) {
        int j = cols[i * CAP + t];
        if (m[j] != 0.f) {
            int s = atomicAdd(&sm.n, 1);
            sm.sc[s] = j;
            if (j == i) sm.sdiag = 1;
        }
    }
    __syncthreads();
    int n = sm.n;
    float4 acc = make_float4(0.f, 0.f, 0.f, 0.f);
    int k = w;
    for (; k + 12 < n; k += 16) {
        float4 v0 = ((const float4*)(A + (size_t)sm.sc[k]      * D))[lane];
        float4 v1 = ((const float4*)(A + (size_t)sm.sc[k + 4]  * D))[lane];
        float4 v2 = ((const float4*)(A + (size_t)sm.sc[k + 8]  * D))[lane];
        float4 v3 = ((const float4*)(A + (size_t)sm.sc[k + 12] * D))[lane];
        acc.x += (v0.x + v1.x) + (v2.x + v3.x);
        acc.y += (v0.y + v1.y) + (v2.y + v3.y);
        acc.z += (v0.z + v1.z) + (v2.z + v3.z);
        acc.w += (v0.w + v1.w) + (v2.w + v3.w);
    }
    for (; k < n; k += 4) {
        float4 v0 = ((const float4*)(A + (size_t)sm.sc[k] * D))[lane];
        acc.x += v0.x; acc.y += v0.y; acc.z += v0.z; acc.w += v0.w;
    }
    *(float4*)&sm.part[w][lane * 4] = acc;
    __syncthreads();
    float av = A[(size_t)i * D + t];
    float hv = H[(size_t)i * D + t];
    float sd = sm.part[0][t] + sm.part[1][t] + sm.part[2][t] + sm.part[3][t];
    float p1 = av * sd, p2 = av * hv, p3 = av * av;
#pragma unroll
    for (int o = 32; o; o >>= 1) {
        p1 += __shfl_down(p1, o);
        p2 += __shfl_down(p2, o);
        p3 += __shfl_down(p3, o);
    }
    if (lane == 0) { sm.r1[w] = p1; sm.r2[w] = p2; sm.r3[w] = p3; }
    __syncthreads();
    if (t == 0) {
        float num  = sm.r1[0] + sm.r1[1] + sm.r1[2] + sm.r1[3];
        float den2 = sm.r2[0] + sm.r2[1] + sm.r2[2] + sm.r2[3];
        float self = sm.r3[0] + sm.r3[1] + sm.r3[2] + sm.r3[3];
        float denom = fmaxf(sqrtf(den2), 1e-12f);
        double inv = 1.0 / (double)denom;
        if (num != 0.f) atomicAdd(total, (double)num * inv);
        if (sm.sdiag) atomicAdd(tr, (double)self * inv);
    }
}

// ---------------------------------------------------------------------------
__global__ void scalars_kernel(const float* __restrict__ cnt,
                               const double* __restrict__ total,
                               const double* __restrict__ tr,
                               float* __restrict__ out) {
    float c = *cnt;
    float T = (float)*total;
    float R = (float)*tr;
    bool has = c > 0.f;
    out[0] = has ? (T / fmaxf(c, 1.f)) : 0.f;                       // pre_avg_degree
    out[1] = has ? (2.f * T / (R * (R - 1.f) + 1e-4f)) : 0.f;       // pre_density
    out[2] = has ? R : 0.f;                                          // pre_avg_nodes
}

// ---------------------------------------------------------------------------
extern "C" void kernel_launch(void* const* d_in, const int* in_sizes, int n_in,
                              void* d_out, int out_size, void* d_ws, size_t ws_size,
                              hipStream_t stream) {
    (void)in_sizes; (void)n_in; (void)out_size; (void)ws_size;
    const float* adj  = (const float*)d_in[0];
    const float* Fda  = (const float*)d_in[1];
    const float* Qadj = (const float*)d_in[2];
    const float* Fq   = (const float*)d_in[3];
    const int*   cand = (const int*)d_in[4];
    // d_in[5] candidate_adj: unused by the reference
    const float* thr  = (const float*)d_in[6];
    const float* W1da = (const float*)d_in[7];
    const float* W1q  = (const float*)d_in[8];
    const float* W2da = (const float*)d_in[9];
    const float* W2q  = (const float*)d_in[10];

    float* out = (float*)d_out;
    float* o_end    = out;                           // [10000]
    float* o_attda2 = out + NDA;                     // [10000,256]
    float* o_attq2  = out + NDA + (size_t)NDA * D;   // [64,256]
    float* o_sc     = o_attq2 + NQ * D;              // [3] scalars

    char* w = (char*)d_ws;
    size_t off = 0;
    auto alloc = [&](size_t b) { size_t r = off; off += (b + 255) & ~(size_t)255; return r; };
    float* bufA = (float*)(w + alloc((size_t)NDA * D * 4));   // X1 -> Y2
    float* bufB = (float*)(w + alloc((size_t)NDA * D * 4));   // da1 -> H
    float* bufC = (float*)(w + alloc((size_t)NDA * D * 4));   // da2
    int* colsb   = (int*)(w + alloc((size_t)NDA * CAP * 4));
    int* rowcntb = (int*)(w + alloc((size_t)NDA * 4));
    float* mbuf  = (float*)(w + alloc((size_t)NDA * 4));
    float* Gb    = (float*)(w + alloc((size_t)D * D * 4));    // G (zeroed in stage0)
    char* zbase = w + alloc(256);                             // scalar accumulators
    float* cntb  = (float*)zbase;
    double* totb = (double*)(zbase + 8);
    double* trb  = (double*)(zbase + 16);
    float* xq   = (float*)(w + alloc((size_t)NQ * D * 4));    // Xq -> Zq
    float* q1b  = (float*)(w + alloc((size_t)NQ * D * 4));
    float* q2b  = (float*)(w + alloc((size_t)NQ * D * 4));
    float* hpart = (float*)(w + alloc((size_t)4 * NQ * D * 4));
    float* embb = (float*)(w + alloc((size_t)(D + 1) * 4));

    // Layer 1
    stage0_kernel<<<NB64 + 20 + NDA, 256, 0, stream>>>(adj, colsb, rowcntb,
                                                       Fda, W1da, bufA, Fq, W1q, xq, Gb);
    stage_sg_kernel<<<NDA + 4, 256, 0, stream>>>(colsb, rowcntb, bufA, bufB, (float*)nullptr,
                                                 Qadj, xq, q1b);                   // q1 | da1
    mergeA_kernel<<<256 + NB64, 256, 0, stream>>>(q1b, bufB, cand, hpart, W2da, bufA); // cross1 | Y2
    qfused_kernel<<<4, 256, 0, stream>>>(q1b, hpart, W2q, xq);                     // att_q1 -> Zq
    // Layer 2
    stage_sg_kernel<<<NDA + 4, 256, 0, stream>>>(colsb, rowcntb, bufA, bufC, o_attda2,
                                                 Qadj, xq, q2b);                   // q2 | da2
    cross_kernel<<<dim3(NQ, 4), 256, 0, stream>>>(q2b, bufC, cand, hpart);
    attq4_kernel<<<4, 256, 0, stream>>>(q2b, hpart, o_attq2, embb, cntb, totb, trb);
    // Scoring: [G (inline mask) | end] merged, then H, then final reduction
    endG_kernel<<<NGB + NDA / 4, 256, 0, stream>>>(o_attda2, embb, thr, o_end, mbuf, cntb, Gb);
    gemmH_kernel<<<dim3((NDA + 63) / 64, D / 64), 256, 0, stream>>>(o_attda2, Gb, bufB);
    final_kernel<<<NDA, 256, 0, stream>>>(colsb, rowcntb, mbuf, o_attda2, bufB, totb, trb);
    scalars_kernel<<<1, 1, 0, stream>>>(cntb, totb, trb, o_sc);
}

// Round 8
// 1028.690 us; speedup vs baseline: 1.1060x; 1.1060x over previous
//
#include <hip/hip_runtime.h>

// Problem constants (fixed by setup_inputs)
constexpr int NDA = 10000;   // target graph nodes
constexpr int NQ  = 64;      // query graph nodes
constexpr int CND = 1024;    // candidate set size
constexpr int DIN = 128;     // input feature dim
constexpr int D   = 256;     // hidden dim
constexpr int CAP = 96;      // max nnz per adjacency row (Poisson(20); P(>96) ~ 0)

#define LRELU(x) ((x) >= 0.f ? (x) : 0.01f * (x))

__device__ __forceinline__ float wave_red64(float v) {
#pragma unroll
    for (int o = 32; o; o >>= 1) v += __shfl_down(v, o);
    return v;
}

// ---------------------------------------------------------------------------
// CSR build: one block per row, scan 10000 floats, record nonzero columns.
__global__ __launch_bounds__(256) void build_csr(const float* __restrict__ adj,
                                                 int* __restrict__ cols,
                                                 int* __restrict__ rowcnt) {
    int row = blockIdx.x;
    __shared__ int scnt;
    if (threadIdx.x == 0) scnt = 0;
    __syncthreads();
    const float4* rp = (const float4*)(adj + (size_t)row * NDA);
    for (int i = threadIdx.x; i < NDA / 4; i += 256) {
        float4 v = rp[i];
        if (v.x != 0.f) { int s = atomicAdd(&scnt, 1); if (s < CAP) cols[row * CAP + s] = 4 * i; }
        if (v.y != 0.f) { int s = atomicAdd(&scnt, 1); if (s < CAP) cols[row * CAP + s] = 4 * i + 1; }
        if (v.z != 0.f) { int s = atomicAdd(&scnt, 1); if (s < CAP) cols[row * CAP + s] = 4 * i + 2; }
        if (v.w != 0.f) { int s = atomicAdd(&scnt, 1); if (s < CAP) cols[row * CAP + s] = 4 * i + 3; }
    }
    __syncthreads();
    if (threadIdx.x == 0) rowcnt[row] = min(scnt, CAP);
}

// ---------------------------------------------------------------------------
// Generic fp32 tiled GEMM: C[M,N] = op(A)[M,K] @ B[K,N].
// 64x64 tile, 256 threads, 4x4 per thread. K % 16 == 0, N % 64 == 0 required.
template <bool RELU_A, bool RELU_C>
__global__ __launch_bounds__(256) void gemm64(const float* __restrict__ A,
                                              const float* __restrict__ B,
                                              float* __restrict__ C,
                                              int M, int N, int K) {
    __shared__ float As[16][68];
    __shared__ float Bs[16][68];
    const int bm = blockIdx.x * 64;
    const int bn = blockIdx.y * 64;
    const int tid = threadIdx.x;
    const int tx = tid & 15, ty = tid >> 4;
    float acc[4][4] = {};
    for (int k0 = 0; k0 < K; k0 += 16) {
        {   // A tile 64x16 -> As[k][m]
            int m = tid >> 2;
            int k4 = (tid & 3) * 4;
            float4 v = make_float4(0.f, 0.f, 0.f, 0.f);
            if (bm + m < M) v = *(const float4*)(A + (size_t)(bm + m) * K + k0 + k4);
            if (RELU_A) { v.x = LRELU(v.x); v.y = LRELU(v.y); v.z = LRELU(v.z); v.w = LRELU(v.w); }
            As[k4 + 0][m] = v.x; As[k4 + 1][m] = v.y; As[k4 + 2][m] = v.z; As[k4 + 3][m] = v.w;
        }
        {   // B tile 16x64 -> Bs[k][n]
            int kk = tid >> 4;
            int n4 = (tid & 15) * 4;
            float4 v = *(const float4*)(B + (size_t)(k0 + kk) * N + bn + n4);
            Bs[kk][n4 + 0] = v.x; Bs[kk][n4 + 1] = v.y; Bs[kk][n4 + 2] = v.z; Bs[kk][n4 + 3] = v.w;
        }
        __syncthreads();
#pragma unroll
        for (int kk = 0; kk < 16; kk++) {
            float av[4], bv[4];
#pragma unroll
            for (int i = 0; i < 4; i++) av[i] = As[kk][ty * 4 + i];
#pragma unroll
            for (int j = 0; j < 4; j++) bv[j] = Bs[kk][tx * 4 + j];
#pragma unroll
            for (int i = 0; i < 4; i++)
#pragma unroll
                for (int j = 0; j < 4; j++) acc[i][j] += av[i] * bv[j];
        }
        __syncthreads();
    }
#pragma unroll
    for (int i = 0; i < 4; i++) {
        int r = bm + ty * 4 + i;
        if (r < M) {
            float4 v;
            v.x = acc[i][0]; v.y = acc[i][1]; v.z = acc[i][2]; v.w = acc[i][3];
            if (RELU_C) { v.x = LRELU(v.x); v.y = LRELU(v.y); v.z = LRELU(v.z); v.w = LRELU(v.w); }
            *(float4*)(C + (size_t)r * N + bn + tx * 4) = v;
        }
    }
}

// ---------------------------------------------------------------------------
// SpMM via CSR: out1 = lrelu(sum of X rows), optional out2 = lrelu(out1).
// Wave-per-neighbor float4 gather (validated in r4->r5): lane l owns
// d = 4l..4l+3; wave w takes neighbors w, w+4, ... with 4 rows in flight.
// 16B/lane loads -> 4x fewer vmem instructions than the scalar layout.
__global__ __launch_bounds__(256) void spmm_csr(const int* __restrict__ cols,
                                                const int* __restrict__ rowcnt,
                                                const float* __restrict__ X,
                                                float* __restrict__ out1,
                                                float* __restrict__ out2) {
    int row = blockIdx.x;
    int t = threadIdx.x;
    int w = t >> 6, lane = t & 63;
    int cnt = rowcnt[row];
    __shared__ int sc[CAP];
    __shared__ float part[4][256];
    if (t < cnt) sc[t] = cols[row * CAP + t];
    __syncthreads();
    float4 acc = make_float4(0.f, 0.f, 0.f, 0.f);
    int k = w;
    for (; k + 12 < cnt; k += 16) {
        float4 v0 = ((const float4*)(X + (size_t)sc[k]      * D))[lane];
        float4 v1 = ((const float4*)(X + (size_t)sc[k + 4]  * D))[lane];
        float4 v2 = ((const float4*)(X + (size_t)sc[k + 8]  * D))[lane];
        float4 v3 = ((const float4*)(X + (size_t)sc[k + 12] * D))[lane];
        acc.x += (v0.x + v1.x) + (v2.x + v3.x);
        acc.y += (v0.y + v1.y) + (v2.y + v3.y);
        acc.z += (v0.z + v1.z) + (v2.z + v3.z);
        acc.w += (v0.w + v1.w) + (v2.w + v3.w);
    }
    for (; k < cnt; k += 4) {
        float4 v0 = ((const float4*)(X + (size_t)sc[k] * D))[lane];
        acc.x += v0.x; acc.y += v0.y; acc.z += v0.z; acc.w += v0.w;
    }
    *(float4*)&part[w][lane * 4] = acc;
    __syncthreads();
    float s = part[0][t] + part[1][t] + part[2][t] + part[3][t];
    float v = LRELU(s);
    out1[(size_t)row * D + t] = v;
    if (out2) out2[(size_t)row * D + t] = LRELU(v);
}

// ---------------------------------------------------------------------------
// Row L2 norms of da[cand[b]] (b<CND) and of q rows (b>=CND).
__global__ __launch_bounds__(256) void rownorms_kernel(const float* __restrict__ da,
                                                       const int* __restrict__ cand,
                                                       float* __restrict__ rnc,
                                                       const float* __restrict__ q,
                                                       float* __restrict__ rnq) {
    int b = blockIdx.x;
    const float* src;
    float* dst;
    if (b < CND) { src = da + (size_t)cand[b] * D; dst = rnc + b; }
    else         { src = q + (size_t)(b - CND) * D; dst = rnq + (b - CND); }
    float v = src[threadIdx.x];
    float p = wave_red64(v * v);
    __shared__ float red[4];
    int w = threadIdx.x >> 6, lane = threadIdx.x & 63;
    if (lane == 0) red[w] = p;
    __syncthreads();
    if (threadIdx.x == 0) *dst = sqrtf(red[0] + red[1] + red[2] + red[3]);
}

// ---------------------------------------------------------------------------
// Cosine matrix c[r,cc] = (q_r . a_cand[cc]) / (max(|q_r|,eps)*max(|a|,eps)).
__global__ __launch_bounds__(256) void cosmat_kernel(const float* __restrict__ q,
                                                     const float* __restrict__ rnq,
                                                     const float* __restrict__ da,
                                                     const int* __restrict__ cand,
                                                     const float* __restrict__ rnc,
                                                     float* __restrict__ cm) {
    __shared__ float qs[D];
    int r = blockIdx.x;
    int cc = blockIdx.y * 256 + threadIdx.x;
    qs[threadIdx.x] = q[r * D + threadIdx.x];
    __syncthreads();
    int row = cand[cc];
    const float4* ap = (const float4*)(da + (size_t)row * D);
    float dot = 0.f;
#pragma unroll 8
    for (int k = 0; k < D / 4; k++) {
        float4 v = ap[k];
        dot += qs[4 * k] * v.x + qs[4 * k + 1] * v.y + qs[4 * k + 2] * v.z + qs[4 * k + 3] * v.w;
    }
    float denom = fmaxf(rnq[r], 1e-12f) * fmaxf(rnc[cc], 1e-12f);
    cm[r * CND + cc] = dot / denom;
}

// ---------------------------------------------------------------------------
// h[r,:] = sum_cc cm[r,cc] * da[cand[cc],:]   (grid NQ, 256 threads)
__global__ __launch_bounds__(256) void hq_kernel(const float* __restrict__ cm,
                                                 const float* __restrict__ da,
                                                 const int* __restrict__ cand,
                                                 float* __restrict__ h) {
    __shared__ float swt[CND];
    __shared__ int sci[CND];
    int r = blockIdx.x, d = threadIdx.x;
    for (int s = 0; s < CND / 256; s++) {
        swt[s * 256 + d] = cm[r * CND + s * 256 + d];
        sci[s * 256 + d] = cand[s * 256 + d];
    }
    __syncthreads();
    float a0 = 0.f, a1 = 0.f, a2 = 0.f, a3 = 0.f, a4 = 0.f, a5 = 0.f, a6 = 0.f, a7 = 0.f;
    for (int c = 0; c < CND; c += 8) {
        a0 += swt[c + 0] * da[(size_t)sci[c + 0] * D + d];
        a1 += swt[c + 1] * da[(size_t)sci[c + 1] * D + d];
        a2 += swt[c + 2] * da[(size_t)sci[c + 2] * D + d];
        a3 += swt[c + 3] * da[(size_t)sci[c + 3] * D + d];
        a4 += swt[c + 4] * da[(size_t)sci[c + 4] * D + d];
        a5 += swt[c + 5] * da[(size_t)sci[c + 5] * D + d];
        a6 += swt[c + 6] * da[(size_t)sci[c + 6] * D + d];
        a7 += swt[c + 7] * da[(size_t)sci[c + 7] * D + d];
    }
    h[r * D + d] = ((a0 + a1) + (a2 + a3)) + ((a4 + a5) + (a6 + a7));
}

// ---------------------------------------------------------------------------
// att_q = lrelu(q + h / max(colnorm(h),1e-12)); optionally emb = mean rows,
// emb[256] = |emb|. Single block, thread d owns column d.
__global__ __launch_bounds__(256) void attq_kernel(const float* __restrict__ q,
                                                   const float* __restrict__ h,
                                                   float* __restrict__ attq,
                                                   float* __restrict__ emb) {
    int d = threadIdx.x;
    float hv[NQ];
    float ss = 0.f;
#pragma unroll
    for (int r = 0; r < NQ; r++) {
        hv[r] = h[r * D + d];
        ss += hv[r] * hv[r];
    }
    float inv = 1.f / fmaxf(sqrtf(ss), 1e-12f);
    float es = 0.f;
#pragma unroll
    for (int r = 0; r < NQ; r++) {
        float v = q[r * D + d] + hv[r] * inv;
        v = LRELU(v);
        attq[r * D + d] = v;
        es += v;
    }
    if (emb) {
        float e = es * (1.f / (float)NQ);
        emb[d] = e;
        float p = wave_red64(e * e);
        __shared__ float red[4];
        int w = d >> 6, lane = d & 63;
        if (lane == 0) red[w] = p;
        __syncthreads();
        if (d == 0) emb[D] = sqrtf(red[0] + red[1] + red[2] + red[3]);
    }
}

// ---------------------------------------------------------------------------
// end[i] = (a_i . emb) / max(|a_i|*|emb|, 1e-8); m[i] = end>thr; cnt += m.
__global__ __launch_bounds__(256) void end_kernel(const float* __restrict__ A,
                                                  const float* __restrict__ emb,
                                                  const float* __restrict__ thr_p,
                                                  float* __restrict__ endv,
                                                  float* __restrict__ m,
                                                  float* __restrict__ cnt) {
    __shared__ float se[D];
    __shared__ float scnt;
    int d = threadIdx.x;
    se[d] = emb[d];
    if (d == 0) scnt = 0.f;
    __syncthreads();
    float embn = emb[D];
    float thr = *thr_p;
    int w = d >> 6, lane = d & 63;
    int row = blockIdx.x * 4 + w;
    const float* ar = A + (size_t)row * D;
    float num = 0.f, sq = 0.f;
#pragma unroll
    for (int s = 0; s < 4; s++) {
        float v = ar[lane + 64 * s];
        num += v * se[lane + 64 * s];
        sq += v * v;
    }
#pragma unroll
    for (int o = 32; o; o >>= 1) { num += __shfl_down(num, o); sq += __shfl_down(sq, o); }
    if (lane == 0) {
        float den = fmaxf(sqrtf(sq) * embn, 1e-8f);
        float e = num / den;
        endv[row] = e;
        float mv = e > thr ? 1.f : 0.f;
        m[row] = mv;
        if (mv != 0.f) atomicAdd(&scnt, 1.f);
    }
    __syncthreads();
    if (d == 0 && scnt != 0.f) atomicAdd(cnt, scnt);
}

// ---------------------------------------------------------------------------
// G = sum_i m_i a_i a_i^T  (256x256), split-K with atomics.
constexpr int GCHUNK = 400;
__global__ __launch_bounds__(256) void G_kernel(const float* __restrict__ A,
                                                const float* __restrict__ m,
                                                float* __restrict__ G) {
    __shared__ float SA[8][64], SB[8][64];
    int ti = blockIdx.x >> 2, tj = blockIdx.x & 3;
    int base = blockIdx.y * GCHUNK;
    int tid = threadIdx.x;
    int tx = tid & 15, ty = tid >> 4;
    float acc[4][4] = {};
    for (int g0 = 0; g0 < GCHUNK; g0 += 8) {
        for (int l = tid; l < 512; l += 256) {
            int rr = l >> 6, c = l & 63;
            int r = base + g0 + rr;
            float mv = m[r];
            SA[rr][c] = A[(size_t)r * D + ti * 64 + c] * mv;
            SB[rr][c] = A[(size_t)r * D + tj * 64 + c];
        }
        __syncthreads();
#pragma unroll
        for (int rr = 0; rr < 8; rr++) {
            float av[4], bv[4];
#pragma unroll
            for (int i = 0; i < 4; i++) av[i] = SA[rr][ty * 4 + i];
#pragma unroll
            for (int j = 0; j < 4; j++) bv[j] = SB[rr][tx * 4 + j];
#pragma unroll
            for (int i = 0; i < 4; i++)
#pragma unroll
                for (int j = 0; j < 4; j++) acc[i][j] += av[i] * bv[j];
        }
        __syncthreads();
    }
#pragma unroll
    for (int i = 0; i < 4; i++)
#pragma unroll
        for (int j = 0; j < 4; j++)
            atomicAdd(&G[(ti * 64 + ty * 4 + i) * D + tj * 64 + tx * 4 + j], acc[i][j]);
}

// ---------------------------------------------------------------------------
// Final reduction per masked row i: compact masked neighbors into LDS, then
// wave-per-neighbor float4 gather (validated r4->r5: removes per-nonzero
// serial wave reductions), then num/den2/self in one reduction pass.
__global__ __launch_bounds__(256) void final_kernel(const int* __restrict__ cols,
                                                    const int* __restrict__ rowcnt,
                                                    const float* __restrict__ m,
                                                    const float* __restrict__ A,
                                                    const float* __restrict__ H,
                                                    double* __restrict__ total,
                                                    double* __restrict__ tr) {
    int i = blockIdx.x;
    if (m[i] == 0.f) return;
    __shared__ int sc[CAP];
    __shared__ float part[4][256];
    __shared__ int sn, sdiag;
    __shared__ float r1[4], r2[4], r3[4];
    int t = threadIdx.x;
    int w = t >> 6, lane = t & 63;
    int cnt = rowcnt[i];
    if (t == 0) { sn = 0; sdiag = 0; }
    __syncthreads();
    if (t < cnt) {
        int j = cols[i * CAP + t];
        if (m[j] != 0.f) {
            int s = atomicAdd(&sn, 1);
            sc[s] = j;
            if (j == i) sdiag = 1;
        }
    }
    __syncthreads();
    int n = sn;
    float4 acc = make_float4(0.f, 0.f, 0.f, 0.f);
    int k = w;
    for (; k + 12 < n; k += 16) {
        float4 v0 = ((const float4*)(A + (size_t)sc[k]      * D))[lane];
        float4 v1 = ((const float4*)(A + (size_t)sc[k + 4]  * D))[lane];
        float4 v2 = ((const float4*)(A + (size_t)sc[k + 8]  * D))[lane];
        float4 v3 = ((const float4*)(A + (size_t)sc[k + 12] * D))[lane];
        acc.x += (v0.x + v1.x) + (v2.x + v3.x);
        acc.y += (v0.y + v1.y) + (v2.y + v3.y);
        acc.z += (v0.z + v1.z) + (v2.z + v3.z);
        acc.w += (v0.w + v1.w) + (v2.w + v3.w);
    }
    for (; k < n; k += 4) {
        float4 v0 = ((const float4*)(A + (size_t)sc[k] * D))[lane];
        acc.x += v0.x; acc.y += v0.y; acc.z += v0.z; acc.w += v0.w;
    }
    *(float4*)&part[w][lane * 4] = acc;
    __syncthreads();
    float av = A[(size_t)i * D + t];
    float hv = H[(size_t)i * D + t];
    float sd = part[0][t] + part[1][t] + part[2][t] + part[3][t];
    float p1 = av * sd, p2 = av * hv, p3 = av * av;
#pragma unroll
    for (int o = 32; o; o >>= 1) {
        p1 += __shfl_down(p1, o);
        p2 += __shfl_down(p2, o);
        p3 += __shfl_down(p3, o);
    }
    if (lane == 0) { r1[w] = p1; r2[w] = p2; r3[w] = p3; }
    __syncthreads();
    if (t == 0) {
        float num  = r1[0] + r1[1] + r1[2] + r1[3];
        float den2 = r2[0] + r2[1] + r2[2] + r2[3];
        float self = r3[0] + r3[1] + r3[2] + r3[3];
        float denom = fmaxf(sqrtf(den2), 1e-12f);
        double inv = 1.0 / (double)denom;
        if (num != 0.f) atomicAdd(total, (double)num * inv);
        if (sdiag) atomicAdd(tr, (double)self * inv);
    }
}

// ---------------------------------------------------------------------------
__global__ void scalars_kernel(const float* __restrict__ cnt,
                               const double* __restrict__ total,
                               const double* __restrict__ tr,
                               float* __restrict__ out) {
    float c = *cnt;
    float T = (float)*total;
    float R = (float)*tr;
    bool has = c > 0.f;
    out[0] = has ? (T / fmaxf(c, 1.f)) : 0.f;                       // pre_avg_degree
    out[1] = has ? (2.f * T / (R * (R - 1.f) + 1e-4f)) : 0.f;       // pre_density
    out[2] = has ? R : 0.f;                                          // pre_avg_nodes
}

// ---------------------------------------------------------------------------
extern "C" void kernel_launch(void* const* d_in, const int* in_sizes, int n_in,
                              void* d_out, int out_size, void* d_ws, size_t ws_size,
                              hipStream_t stream) {
    (void)in_sizes; (void)n_in; (void)out_size; (void)ws_size;
    const float* adj  = (const float*)d_in[0];
    const float* Fda  = (const float*)d_in[1];
    const float* Qadj = (const float*)d_in[2];
    const float* Fq   = (const float*)d_in[3];
    const int*   cand = (const int*)d_in[4];
    // d_in[5] candidate_adj: unused by the reference
    const float* thr  = (const float*)d_in[6];
    const float* W1da = (const float*)d_in[7];
    const float* W1q  = (const float*)d_in[8];
    const float* W2da = (const float*)d_in[9];
    const float* W2q  = (const float*)d_in[10];

    float* out = (float*)d_out;
    float* o_end    = out;                       // [10000]
    float* o_attda2 = out + NDA;                 // [10000,256]
    float* o_attq2  = out + NDA + (size_t)NDA * D;       // [64,256]
    float* o_sc     = o_attq2 + NQ * D;          // [3] scalars

    char* w = (char*)d_ws;
    size_t off = 0;
    auto alloc = [&](size_t b) { size_t r = off; off += (b + 255) & ~(size_t)255; return r; };
    float* bufA = (float*)(w + alloc((size_t)NDA * D * 4));   // X1 -> Y2
    float* bufB = (float*)(w + alloc((size_t)NDA * D * 4));   // da1 -> H
    float* bufC = (float*)(w + alloc((size_t)NDA * D * 4));   // da2
    int* colsb   = (int*)(w + alloc((size_t)NDA * CAP * 4));
    int* rowcntb = (int*)(w + alloc((size_t)NDA * 4));
    float* mbuf  = (float*)(w + alloc((size_t)NDA * 4));
    char* zbase = w + alloc(262144 + 256);                    // G + scalar accumulators
    float* Gb    = (float*)zbase;
    float* cntb  = (float*)(zbase + 262144);
    double* totb = (double*)(zbase + 262144 + 8);
    double* trb  = (double*)(zbase + 262144 + 16);
    float* xq   = (float*)(w + alloc((size_t)NQ * D * 4));    // Xq -> Zq
    float* q1b  = (float*)(w + alloc((size_t)NQ * D * 4));
    float* aq1  = (float*)(w + alloc((size_t)NQ * D * 4));
    float* q2b  = (float*)(w + alloc((size_t)NQ * D * 4));
    float* hb   = (float*)(w + alloc((size_t)NQ * D * 4));
    float* cm   = (float*)(w + alloc((size_t)NQ * CND * 4));
    float* rnc  = (float*)(w + alloc((size_t)CND * 4));
    float* rnq  = (float*)(w + alloc((size_t)NQ * 4));
    float* embb = (float*)(w + alloc((size_t)(D + 1) * 4));

    hipMemsetAsync(zbase, 0, 262144 + 256, stream);

    const dim3 gBig((NDA + 63) / 64, D / 64);
    const dim3 gSmall(1, D / 64);

    // Layer 1
    gemm64<false, false><<<gBig, 256, 0, stream>>>(Fda, W1da, bufA, NDA, D, DIN);   // X1
    build_csr<<<NDA, 256, 0, stream>>>(adj, colsb, rowcntb);
    gemm64<false, false><<<gSmall, 256, 0, stream>>>(Fq, W1q, xq, NQ, D, DIN);      // Xq
    gemm64<false, true><<<gSmall, 256, 0, stream>>>(Qadj, xq, q1b, NQ, D, NQ);      // q1
    spmm_csr<<<NDA, 256, 0, stream>>>(colsb, rowcntb, bufA, bufB, (float*)nullptr); // da1
    rownorms_kernel<<<CND + NQ, 256, 0, stream>>>(bufB, cand, rnc, q1b, rnq);
    cosmat_kernel<<<dim3(NQ, CND / 256), 256, 0, stream>>>(q1b, rnq, bufB, cand, rnc, cm);
    hq_kernel<<<NQ, 256, 0, stream>>>(cm, bufB, cand, hb);                           // h1
    attq_kernel<<<1, 256, 0, stream>>>(q1b, hb, aq1, (float*)nullptr);               // att_q1
    // Layer 2
    gemm64<true, false><<<gBig, 256, 0, stream>>>(bufB, W2da, bufA, NDA, D, D);      // Y2 = lrelu(da1)@W2
    gemm64<false, false><<<gSmall, 256, 0, stream>>>(aq1, W2q, xq, NQ, D, D);        // Zq
    gemm64<false, true><<<gSmall, 256, 0, stream>>>(Qadj, xq, q2b, NQ, D, NQ);       // q2
    spmm_csr<<<NDA, 256, 0, stream>>>(colsb, rowcntb, bufA, bufC, o_attda2);         // da2 + att_da2
    rownorms_kernel<<<CND + NQ, 256, 0, stream>>>(bufC, cand, rnc, q2b, rnq);
    cosmat_kernel<<<dim3(NQ, CND / 256), 256, 0, stream>>>(q2b, rnq, bufC, cand, rnc, cm);
    hq_kernel<<<NQ, 256, 0, stream>>>(cm, bufC, cand, hb);                           // h2
    attq_kernel<<<1, 256, 0, stream>>>(q2b, hb, o_attq2, embb);                      // att_q2 + emb
    // Scoring
    end_kernel<<<NDA / 4, 256, 0, stream>>>(o_attda2, embb, thr, o_end, mbuf, cntb);
    G_kernel<<<dim3(16, NDA / GCHUNK), 256, 0, stream>>>(o_attda2, mbuf, Gb);
    gemm64<false, false><<<gBig, 256, 0, stream>>>(o_attda2, Gb, bufB, NDA, D, D);   // H = A@G
    final_kernel<<<NDA, 256, 0, stream>>>(colsb, rowcntb, mbuf, o_attda2, bufB, totb, trb);
    scalars_kernel<<<1, 1, 0, stream>>>(cntb, totb, trb, o_sc);
}